// Round 1
// baseline (564.237 us; speedup 1.0000x reference)
//
#include <hip/hip_runtime.h>
#include <hip/hip_bf16.h>

#define DIM    16
#define BATCH  32
#define KL     4
#define NTS    512
#define NC     4
#define NPAR   16
#define DTF    (1.0f/512.0f)
#define BST    40     // bf16 operand row stride (ushort)
#define FST    20     // f32 tile row stride

using short8  = __attribute__((ext_vector_type(8))) short;
using short4v = __attribute__((ext_vector_type(4))) short;
using f32x4   = __attribute__((ext_vector_type(4))) float;

__device__ __forceinline__ float b2f(__hip_bfloat16 x) { return __bfloat162float(x); }

__device__ __forceinline__ float ldval(const void* p, int idx, bool isf32) {
  return isf32 ? ((const float*)p)[idx]
               : __bfloat162float(((const __hip_bfloat16*)p)[idx]);
}
__device__ __forceinline__ unsigned short f2bf(float x) {   // RNE (setup/L only)
  unsigned u = __float_as_uint(x);
  unsigned r = u + 0x7FFFu + ((u >> 16) & 1u);
  return (unsigned short)(r >> 16);
}
__device__ __forceinline__ float bf2f(unsigned short h) {
  return __uint_as_float(((unsigned)h) << 16);
}
// trunc-trunc hi/lo split (R10-verified)
__device__ __forceinline__ void split2(float v, unsigned short& h, unsigned short& l) {
  unsigned u = __float_as_uint(v);
  h = (unsigned short)(u >> 16);
  float r = v - __uint_as_float(u & 0xFFFF0000u);
  l = (unsigned short)(__float_as_uint(r) >> 16);
}
__device__ __forceinline__ short8 ldfrag(const unsigned short* p) {
  return *(const short8*)p;
}
__device__ __forceinline__ short8 negbf8(short8 a) {
  union { short8 s; unsigned u[4]; } v; v.s = a;
  #pragma unroll
  for (int q = 0; q < 4; ++q) v.u[q] ^= 0x80008000u;
  return v.s;
}
__device__ __forceinline__ f32x4 mm3(short8 Ah, short8 Al, short8 Bh, short8 Bl, f32x4 acc) {
  acc = __builtin_amdgcn_mfma_f32_16x16x32_bf16(Ah, Bh, acc, 0, 0, 0);
  acc = __builtin_amdgcn_mfma_f32_16x16x32_bf16(Al, Bh, acc, 0, 0, 0);
  acc = __builtin_amdgcn_mfma_f32_16x16x32_bf16(Ah, Bl, acc, 0, 0, 0);
  return acc;
}
// trunc hi/lo pack of f32x4 via v_perm_b32 — bit-identical to split2, ~half the VALU ops
__device__ __forceinline__ void pack4(f32x4 v, short4v& hi, short4v& lo) {
  union { short4v s; unsigned d[2]; } H, L;
  unsigned u0 = __float_as_uint(v[0]), u1 = __float_as_uint(v[1]);
  unsigned u2 = __float_as_uint(v[2]), u3 = __float_as_uint(v[3]);
  H.d[0] = __builtin_amdgcn_perm(u1, u0, 0x07060302u);   // [hi(v1)|hi(v0)]
  H.d[1] = __builtin_amdgcn_perm(u3, u2, 0x07060302u);
  float r0 = v[0] - __uint_as_float(u0 & 0xFFFF0000u);
  float r1 = v[1] - __uint_as_float(u1 & 0xFFFF0000u);
  float r2 = v[2] - __uint_as_float(u2 & 0xFFFF0000u);
  float r3 = v[3] - __uint_as_float(u3 & 0xFFFF0000u);
  L.d[0] = __builtin_amdgcn_perm(__float_as_uint(r1), __float_as_uint(r0), 0x07060302u);
  L.d[1] = __builtin_amdgcn_perm(__float_as_uint(r3), __float_as_uint(r2), 0x07060302u);
  hi = H.s; lo = L.s;
}
__device__ __forceinline__ void pack8(const float* v, short8& hi, short8& lo) {
  union { short8 s; unsigned d[4]; } H, L;
  #pragma unroll
  for (int j = 0; j < 4; ++j) {
    unsigned ua = __float_as_uint(v[2*j]), ub = __float_as_uint(v[2*j+1]);
    H.d[j] = __builtin_amdgcn_perm(ub, ua, 0x07060302u);
    float ra = v[2*j]   - __uint_as_float(ua & 0xFFFF0000u);
    float rb = v[2*j+1] - __uint_as_float(ub & 0xFFFF0000u);
    L.d[j] = __builtin_amdgcn_perm(__float_as_uint(rb), __float_as_uint(ra), 0x07060302u);
  }
  hi = H.s; lo = L.s;
}

// 2-wave structure: wv0 = {Mr, T(k=0,1), Jr + re-update}, wv1 = {Mi, T(k=2,3), Ji + im-update}.
// All fragment layouts / LDS addresses identical to the verified 8-wave kernel; only the
// wave->work mapping changed. d1 (= M[row0+q][fm]) is the wave's OWN accumulator now, so
// the transposed sMrT/sMiT round-trip is deleted. Every LDS RAW dep still crosses a barrier.
__global__ __launch_bounds__(128, 1)
void lindblad_evolve(const void* __restrict__ g_params,
                     const void* __restrict__ g_H0re, const void* __restrict__ g_H0im,
                     const void* __restrict__ g_Hcre, const void* __restrict__ g_Hcim,
                     const void* __restrict__ g_Lre,  const void* __restrict__ g_Lim,
                     const void* __restrict__ g_r0re, const void* __restrict__ g_r0im,
                     float* __restrict__ g_out)
{
  __shared__ __align__(16) unsigned short sPh[16*BST], sPl[16*BST];         // rho^T' hi/lo
  __shared__ __align__(16) unsigned short sTh[KL][16*BST], sTl[KL][16*BST]; // T_k row-major [Tr|Ti]
  __shared__ __align__(16) unsigned short sLh[KL][16*BST], sLl[KL][16*BST]; // L'_k
  __shared__ __align__(16) float sMr[16*FST], sMi[16*FST];    // M normal layout only
  __shared__ __align__(16) float sU[NTS][NC];
  __shared__ __align__(16) float sPops[NTS*DIM];  // pops; first 2560 f32 = setup G-scratch
  __shared__ int sFlag;

  const int tid = threadIdx.x;       // 0..127 (2 waves)
  const int b   = blockIdx.x;
  const int wv  = tid >> 6;          // 0: re-component wave | 1: im-component wave
  const int ln  = tid & 63;
  const int fm  = ln & 15;
  const int fq  = ln >> 4;
  const int row0 = fq * 4;
  const int fOff  = fm*BST + fq*8;
  const int fOffS = fm*BST + ((fq*8 + 16) & 31);

  // ---- input storage-dtype detection (R1/R2-verified) ----
  if (tid == 0) sFlag = 0;
  __syncthreads();
  for (int e = tid; e < 256; e += 128) {
    float v = b2f(((const __hip_bfloat16*)g_H0re)[e]);
    if (!(fabsf(v) <= 1e10f)) atomicOr(&sFlag, 1);
  }
  __syncthreads();
  const bool isf32 = (sFlag != 0);

  // ---- B-spline control pulses (128 threads: 4 passes) ----
  for (int t0 = tid; t0 < NTS; t0 += 128) {
    float kn[20];
    kn[0] = 0.f; kn[1] = 0.f; kn[2] = 0.f;
    #pragma unroll
    for (int q = 0; q < 14; ++q) kn[3 + q] = (float)q / 13.0f;
    kn[17] = 1.f; kn[18] = 1.f; kn[19] = 1.f;
    const float t = (float)t0 * DTF;
    float B[19];
    #pragma unroll
    for (int q = 0; q < 19; ++q) B[q] = (kn[q] <= t && t < kn[q+1]) ? 1.f : 0.f;
    #pragma unroll
    for (int d = 1; d <= 3; ++d) {
      #pragma unroll
      for (int q = 0; q + d < 19; ++q) {
        float ld = kn[q+d]   - kn[q];
        float rd = kn[q+d+1] - kn[q+1];
        float lv = (ld > 0.f) ? (t - kn[q])     / ld * B[q]   : 0.f;
        float rv = (rd > 0.f) ? (kn[q+d+1] - t) / rd * B[q+1] : 0.f;
        B[q] = lv + rv;
      }
    }
    #pragma unroll
    for (int c = 0; c < NC; ++c) {
      float s = 0.f;
      #pragma unroll
      for (int q = 0; q < NPAR; ++q) s += B[q] * ldval(g_params, q*NC + c, isf32);
      sU[t0][c] = s;
    }
  }

  // ---- constants staging (128 threads: 2 passes, elementwise (i,j)) ----
  for (int e = tid; e < 256; e += 128) {
    float* scr = sPops;   // planes: 0=G0r 1=G0i 2+2c=Gc_r 3+2c=Gc_i
    const int i = e >> 4, j = e & 15;
    const int ij = i*16 + j, ji = j*16 + i;
    float h0r = 0.5f * (ldval(g_H0re, ij, isf32) + ldval(g_H0re, ji, isf32));
    float h0i = 0.5f * (ldval(g_H0im, ij, isf32) - ldval(g_H0im, ji, isf32));
    float ldr = 0.f, ldi = 0.f;
    for (int k = 0; k < KL; ++k) {
      #pragma unroll
      for (int m = 0; m < DIM; ++m) {
        float ar = ldval(g_Lre, k*256 + m*16 + i, isf32), ai = ldval(g_Lim, k*256 + m*16 + i, isf32);
        float br = ldval(g_Lre, k*256 + m*16 + j, isf32), bi = ldval(g_Lim, k*256 + m*16 + j, isf32);
        ldr += ar*br + ai*bi;
        ldi += ar*bi - ai*br;
      }
    }
    scr[0*256 + ij] =  h0i - 0.5f*ldr;   // G0r
    scr[1*256 + ij] = -h0r - 0.5f*ldi;   // G0i
    #pragma unroll
    for (int c = 0; c < NC; ++c) {
      float hr = 0.5f * (ldval(g_Hcre, c*256 + ij, isf32) + ldval(g_Hcre, c*256 + ji, isf32));
      float hi = 0.5f * (ldval(g_Hcim, c*256 + ij, isf32) - ldval(g_Hcim, c*256 + ji, isf32));
      scr[(2 + 2*c)*256 + ij] =  hi;
      scr[(3 + 2*c)*256 + ij] = -hr;
    }
    // L': RNE hi/lo split
    #pragma unroll
    for (int k = 0; k < KL; ++k) {
      float lr = ldval(g_Lre, k*256 + ij, isf32);
      float li = ldval(g_Lim, k*256 + ij, isf32);
      unsigned short h;
      h = f2bf(lr); sLh[k][i*BST + j]      = h; sLl[k][i*BST + j]      = f2bf(lr - bf2f(h));
      h = f2bf(li); sLh[k][i*BST + 16 + j] = h; sLl[k][i*BST + 16 + j] = f2bf(li - bf2f(h));
    }
    // rho^T'(0)
    float r0 = ldval(g_r0re, b*256 + ij, isf32);
    float m0 = ldval(g_r0im, b*256 + ij, isf32);
    unsigned short h, l;
    split2(r0, h, l); sPh[j*BST + i]      = h; sPl[j*BST + i]      = l;
    split2(m0, h, l); sPh[j*BST + 16 + i] = h; sPl[j*BST + 16 + i] = l;
  }

  __syncthreads();   // scratch, sL, sP, sU visible

  // ---- per-wave preloads ----
  short8 Ah, Al;                    // G frag (rebuilt per step, both waves hold it)
  float  G0v[8], Gcv[NC][8];
  {
    const int comp = (fq < 2) ? 0 : 1;
    const int base = (fq & 1) * 8;
    const float* scr = sPops;
    {
      const float* s0 = &scr[comp*256 + fm*16 + base];
      f32x4 va = *(const f32x4*)s0, vb = *(const f32x4*)(s0 + 4);
      #pragma unroll
      for (int q = 0; q < 4; ++q) { G0v[q] = va[q]; G0v[4+q] = vb[q]; }
    }
    #pragma unroll
    for (int c = 0; c < NC; ++c) {
      const float* s0 = &scr[(2 + 2*c + comp)*256 + fm*16 + base];
      f32x4 va = *(const f32x4*)s0, vb = *(const f32x4*)(s0 + 4);
      #pragma unroll
      for (int q = 0; q < 4; ++q) { Gcv[c][q] = va[q]; Gcv[c][4+q] = vb[q]; }
    }
    f32x4 uv = *(const f32x4*)&sU[0][0];
    float gv[8];
    #pragma unroll
    for (int q = 0; q < 8; ++q)
      gv[q] = G0v[q] + uv[0]*Gcv[0][q] + uv[1]*Gcv[1][q] + uv[2]*Gcv[2][q] + uv[3]*Gcv[3][q];
    pack8(gv, Ah, Al);
  }

  // T B-operand constants for this wave's two k's (k = 2*wv + j)
  short8 TiBh[2], TiBl[2], TrBh[2], TrBl[2];
  #pragma unroll
  for (int j = 0; j < 2; ++j) {
    const int k = 2*wv + j;
    TiBh[j] = ldfrag(&sLh[k][fOff]);
    TiBl[j] = ldfrag(&sLl[k][fOff]);
    TrBh[j] = (fq >= 2) ? negbf8(TiBh[j]) : TiBh[j];
    TrBl[j] = (fq >= 2) ? negbf8(TiBl[j]) : TiBl[j];
  }

  // J A-operand constants + rho C-layout preload
  short8 JBh[KL], JBl[KL];
  float  rm[4];
  if (wv == 0) {
    // Jr^T = [Lr|Li](A) x [Tr^T; Ti^T](B) -> A = straight L-frag
    #pragma unroll
    for (int k = 0; k < KL; ++k) { JBh[k] = ldfrag(&sLh[k][fOff]); JBl[k] = ldfrag(&sLl[k][fOff]); }
    #pragma unroll
    for (int q = 0; q < 4; ++q) rm[q] = ldval(g_r0re, b*256 + (row0+q)*16 + fm, isf32);
  } else {
    // Ji^T = [-Li|Lr](A) x [Tr^T; Ti^T](B) -> A = swap+neg
    #pragma unroll
    for (int k = 0; k < KL; ++k) {
      short8 h = ldfrag(&sLh[k][fOffS]);
      short8 l = ldfrag(&sLl[k][fOffS]);
      if (fq < 2) { h = negbf8(h); l = negbf8(l); }
      JBh[k] = h; JBl[k] = l;
    }
    #pragma unroll
    for (int q = 0; q < 4; ++q) rm[q] = ldval(g_r0im, b*256 + (row0+q)*16 + fm, isf32);
  }

  float* const Mn = (wv == 0) ? sMr : sMi;

  // ---- main Euler loop: 2 barriers/step, 2 symmetric waves ----
  #pragma unroll 1
  for (int t = 0; t < NTS; ++t) {
    __syncthreads();   // B1: sP(t) visible (cross-wave: re half from wv0, im half from wv1)

    // shared rho fragments (A-layout: straight and half-swapped)
    short8 Pfh = ldfrag(&sPh[fOff]),  Pfl = ldfrag(&sPl[fOff]);    // [rho_r^T|rho_i^T]
    short8 Psh = ldfrag(&sPh[fOffS]), Psl = ldfrag(&sPl[fOffS]);   // [rho_i^T|rho_r^T]

    // ---- M component: wv0 -> Mr = Re(G rho), wv1 -> Mi = Im(G rho) ----
    short8 MBh, MBl;
    if (wv == 0) {
      MBh = Pfh; MBl = Pfl;
      if (fq >= 2) { MBh = negbf8(MBh); MBl = negbf8(MBl); }       // B = [rho_r ; -rho_i]
    } else {
      MBh = Psh; MBl = Psl;                                        // B = [rho_i ;  rho_r]
    }
    f32x4 mAcc = {0.f,0.f,0.f,0.f};
    mAcc = mm3(Ah, Al, MBh, MBl, mAcc);        // lane owns M[row0+q][fm] == d1

    // ---- T^T producer for this wave's two k's ----
    #pragma unroll
    for (int j = 0; j < 2; ++j) {
      const int k = 2*wv + j;
      f32x4 tr = {0.f,0.f,0.f,0.f}, ti = {0.f,0.f,0.f,0.f};
      tr = mm3(Pfh, Pfl, TrBh[j], TrBl[j], tr);    // Tr^T tile
      ti = mm3(Psh, Psl, TiBh[j], TiBl[j], ti);    // Ti^T tile
      short4v HR, LR, HI2, LI2;
      pack4(tr, HR, LR);
      pack4(ti, HI2, LI2);
      *(short4v*)&sTh[k][fm*BST + row0]      = HR;
      *(short4v*)&sTl[k][fm*BST + row0]      = LR;
      *(short4v*)&sTh[k][fm*BST + 16 + row0] = HI2;
      *(short4v*)&sTl[k][fm*BST + 16 + row0] = LI2;
    }

    // M normal-layout write (same-wave consumer in phase 2 reads the transpose)
    #pragma unroll
    for (int r = 0; r < 4; ++r) Mn[(row0 + r)*FST + fm] = mAcc[r];

    __syncthreads();   // B2: sT visible (cross-wave)

    // ---- J^T + update: wv0 -> Jr^T (= Jr, symmetric), wv1 -> Ji^T (= -Ji) ----
    short8 T0h = ldfrag(&sTh[0][fOff]), T0l = ldfrag(&sTl[0][fOff]);
    short8 T1h = ldfrag(&sTh[1][fOff]), T1l = ldfrag(&sTl[1][fOff]);
    short8 T2h = ldfrag(&sTh[2][fOff]), T2l = ldfrag(&sTl[2][fOff]);
    short8 T3h = ldfrag(&sTh[3][fOff]), T3l = ldfrag(&sTl[3][fOff]);
    f32x4 d2 = *(const f32x4*)&Mn[fm*FST + row0];   // M[fm][row0+q] = M^T element (own write, phase 1)
    f32x4 a0 = {0.f,0.f,0.f,0.f}, a1 = {0.f,0.f,0.f,0.f},
          a2 = {0.f,0.f,0.f,0.f}, a3 = {0.f,0.f,0.f,0.f};
    a0 = mm3(JBh[0], JBl[0], T0h, T0l, a0);
    a1 = mm3(JBh[1], JBl[1], T1h, T1l, a1);
    a2 = mm3(JBh[2], JBl[2], T2h, T2l, a2);
    a3 = mm3(JBh[3], JBl[3], T3h, T3l, a3);

    short4v HH, LL;
    if (wv == 0) {
      f32x4 rv;
      #pragma unroll
      for (int q = 0; q < 4; ++q) {
        rm[q] += DTF * (mAcc[q] + d2[q] + ((a0[q] + a1[q]) + (a2[q] + a3[q])));
        rv[q] = rm[q];
      }
      pack4(rv, HH, LL);
      *(short4v*)&sPh[fm*BST + row0] = HH;
      *(short4v*)&sPl[fm*BST + row0] = LL;
      if ((unsigned)(fm - row0) < 4u) sPops[t*DIM + fm] = rm[fm - row0];
    } else {
      f32x4 rv;
      #pragma unroll
      for (int q = 0; q < 4; ++q) {
        // computed = Ji^T = -Ji at own element -> subtract; -Mi^T from d2
        rm[q] += DTF * (mAcc[q] - d2[q] - ((a0[q] + a1[q]) + (a2[q] + a3[q])));
        rv[q] = rm[q];
      }
      pack4(rv, HH, LL);
      *(short4v*)&sPh[fm*BST + 16 + row0] = HH;
      *(short4v*)&sPl[fm*BST + 16 + row0] = LL;
    }

    // ---- G-rebuild for step t+1 (registers only, overlaps MFMA/LDS latency) ----
    {
      const int tn = (t + 1 < NTS) ? (t + 1) : t;
      f32x4 uv = *(const f32x4*)&sU[tn][0];
      float gv[8];
      #pragma unroll
      for (int q = 0; q < 8; ++q)
        gv[q] = G0v[q] + uv[0]*Gcv[0][q] + uv[1]*Gcv[1][q] + uv[2]*Gcv[2][q] + uv[3]*Gcv[3][q];
      pack8(gv, Ah, Al);
    }
  }

  // ---- final coalesced pops flush (float4) ----
  __syncthreads();
  #pragma unroll
  for (int s = 0; s < NTS*DIM/(128*4); ++s) {
    int idx = (s*128 + tid) * 4;                 // idx = t*16 + d, d 4-aligned
    int tt = idx >> 4, dd = idx & 15;
    *(float4*)&g_out[tt*(BATCH*DIM) + b*DIM + dd] = *(const float4*)&sPops[idx];
  }
}

extern "C" void kernel_launch(void* const* d_in, const int* in_sizes, int n_in,
                              void* d_out, int out_size, void* d_ws, size_t ws_size,
                              hipStream_t stream) {
  (void)out_size; (void)d_ws; (void)ws_size;
  const void *P, *H0r, *H0i, *Hcr, *Hci, *Lr, *Li, *R0r, *R0i;
  int idx64 = -1;
  for (int q = 0; q < n_in; ++q) if (in_sizes[q] == 64) idx64 = q;
  if (idx64 == 6) {   // alphabetical fallback
    H0i = d_in[0]; H0r = d_in[1];
    Hci = d_in[2]; Hcr = d_in[3];
    Li  = d_in[4]; Lr  = d_in[5];
    P   = d_in[6];
    R0i = d_in[7]; R0r = d_in[8];
  } else {            // documented setup_inputs() dict order (R4-verified)
    P   = d_in[0];
    H0r = d_in[1]; H0i = d_in[2];
    Hcr = d_in[3]; Hci = d_in[4];
    Lr  = d_in[5]; Li  = d_in[6];
    R0r = d_in[7]; R0i = d_in[8];
  }
  lindblad_evolve<<<dim3(BATCH), dim3(128), 0, stream>>>(
      P, H0r, H0i, Hcr, Hci, Lr, Li, R0r, R0i, (float*)d_out);
}

// Round 2
// 556.299 us; speedup vs baseline: 1.0143x; 1.0143x over previous
//
#include <hip/hip_runtime.h>
#include <hip/hip_bf16.h>

#define DIM    16
#define BATCH  32
#define KL     4
#define NTS    512
#define NC     4
#define NPAR   16
#define DTF    (1.0f/512.0f)
#define BST    40     // bf16 operand row stride (ushort)
#define FST    20     // f32 tile row stride

using short8  = __attribute__((ext_vector_type(8))) short;
using short4v = __attribute__((ext_vector_type(4))) short;
using f32x4   = __attribute__((ext_vector_type(4))) float;

__device__ __forceinline__ float b2f(__hip_bfloat16 x) { return __bfloat162float(x); }

__device__ __forceinline__ float ldval(const void* p, int idx, bool isf32) {
  return isf32 ? ((const float*)p)[idx]
               : __bfloat162float(((const __hip_bfloat16*)p)[idx]);
}
__device__ __forceinline__ unsigned short f2bf(float x) {   // RNE (setup/L only)
  unsigned u = __float_as_uint(x);
  unsigned r = u + 0x7FFFu + ((u >> 16) & 1u);
  return (unsigned short)(r >> 16);
}
__device__ __forceinline__ float bf2f(unsigned short h) {
  return __uint_as_float(((unsigned)h) << 16);
}
// trunc-trunc hi/lo split (R10-verified)
__device__ __forceinline__ void split2(float v, unsigned short& h, unsigned short& l) {
  unsigned u = __float_as_uint(v);
  h = (unsigned short)(u >> 16);
  float r = v - __uint_as_float(u & 0xFFFF0000u);
  l = (unsigned short)(__float_as_uint(r) >> 16);
}
__device__ __forceinline__ short8 ldfrag(const unsigned short* p) {
  return *(const short8*)p;
}
__device__ __forceinline__ short8 negbf8(short8 a) {
  union { short8 s; unsigned u[4]; } v; v.s = a;
  #pragma unroll
  for (int q = 0; q < 4; ++q) v.u[q] ^= 0x80008000u;
  return v.s;
}
__device__ __forceinline__ f32x4 mm3(short8 Ah, short8 Al, short8 Bh, short8 Bl, f32x4 acc) {
  acc = __builtin_amdgcn_mfma_f32_16x16x32_bf16(Ah, Bh, acc, 0, 0, 0);
  acc = __builtin_amdgcn_mfma_f32_16x16x32_bf16(Al, Bh, acc, 0, 0, 0);
  acc = __builtin_amdgcn_mfma_f32_16x16x32_bf16(Ah, Bl, acc, 0, 0, 0);
  return acc;
}
// trunc hi/lo pack of f32x4 via v_perm_b32 — bit-identical to split2 (verified R0 pass)
__device__ __forceinline__ void pack4(f32x4 v, short4v& hi, short4v& lo) {
  union { short4v s; unsigned d[2]; } H, L;
  unsigned u0 = __float_as_uint(v[0]), u1 = __float_as_uint(v[1]);
  unsigned u2 = __float_as_uint(v[2]), u3 = __float_as_uint(v[3]);
  H.d[0] = __builtin_amdgcn_perm(u1, u0, 0x07060302u);   // [hi(v1)|hi(v0)]
  H.d[1] = __builtin_amdgcn_perm(u3, u2, 0x07060302u);
  float r0 = v[0] - __uint_as_float(u0 & 0xFFFF0000u);
  float r1 = v[1] - __uint_as_float(u1 & 0xFFFF0000u);
  float r2 = v[2] - __uint_as_float(u2 & 0xFFFF0000u);
  float r3 = v[3] - __uint_as_float(u3 & 0xFFFF0000u);
  L.d[0] = __builtin_amdgcn_perm(__float_as_uint(r1), __float_as_uint(r0), 0x07060302u);
  L.d[1] = __builtin_amdgcn_perm(__float_as_uint(r3), __float_as_uint(r2), 0x07060302u);
  hi = H.s; lo = L.s;
}
__device__ __forceinline__ void pack8(const float* v, short8& hi, short8& lo) {
  union { short8 s; unsigned d[4]; } H, L;
  #pragma unroll
  for (int j = 0; j < 4; ++j) {
    unsigned ua = __float_as_uint(v[2*j]), ub = __float_as_uint(v[2*j+1]);
    H.d[j] = __builtin_amdgcn_perm(ub, ua, 0x07060302u);
    float ra = v[2*j]   - __uint_as_float(ua & 0xFFFF0000u);
    float rb = v[2*j+1] - __uint_as_float(ub & 0xFFFF0000u);
    L.d[j] = __builtin_amdgcn_perm(__float_as_uint(rb), __float_as_uint(ra), 0x07060302u);
  }
  hi = H.s; lo = L.s;
}

// R1: dual-chain interleave. One block evolves TWO batch elements (chains 0/1) with the
// verified 8-wave per-chain code, phase-shifted by half a step so every wave class
// (M: wv0/1, T: wv2-5, J: wv6/7) is busy in BOTH phases. Both chains sit at the same t,
// so one G-rebuild per iteration serves both M computations. All per-chain LDS state is
// duplicated; every cross-wave RAW dependency still crosses exactly one barrier.
__global__ __launch_bounds__(512, 1)
void lindblad_evolve(const void* __restrict__ g_params,
                     const void* __restrict__ g_H0re, const void* __restrict__ g_H0im,
                     const void* __restrict__ g_Hcre, const void* __restrict__ g_Hcim,
                     const void* __restrict__ g_Lre,  const void* __restrict__ g_Lim,
                     const void* __restrict__ g_r0re, const void* __restrict__ g_r0im,
                     float* __restrict__ g_out)
{
  __shared__ __align__(16) unsigned short sPh[2][16*BST], sPl[2][16*BST];          // rho^T' hi/lo per chain
  __shared__ __align__(16) unsigned short sTh[2][KL][16*BST], sTl[2][KL][16*BST];  // T_k per chain
  __shared__ __align__(16) unsigned short sLh[KL][16*BST], sLl[KL][16*BST];        // L'_k (shared)
  __shared__ __align__(16) float sMr[2][16*FST],  sMi[2][16*FST];    // M normal layout per chain
  __shared__ __align__(16) float sMrT[2][16*FST], sMiT[2][16*FST];   // M transposed per chain
  __shared__ __align__(16) float sU[NTS][NC];
  __shared__ __align__(16) float sPops[2][NTS*DIM];  // per-chain pops; sPops[0][0..2559] = setup G-scratch
  __shared__ int sFlag;

  const int tid = threadIdx.x;       // 0..511 (8 waves)
  const int b0  = 2*blockIdx.x;      // chain 0 batch index
  const int b1  = b0 + 1;            // chain 1 batch index
  const int wv  = tid >> 6;          // 0,1: M | 2-5: T_k | 6,7: J+update
  const int ln  = tid & 63;
  const int fm  = ln & 15;
  const int fq  = ln >> 4;
  const int row0 = fq * 4;
  const int fOff  = fm*BST + fq*8;
  const int fOffS = fm*BST + ((fq*8 + 16) & 31);

  // ---- input storage-dtype detection (R1/R2-verified) ----
  if (tid == 0) sFlag = 0;
  __syncthreads();
  if (tid < 256) {
    float v = b2f(((const __hip_bfloat16*)g_H0re)[tid]);
    if (!(fabsf(v) <= 1e10f)) atomicOr(&sFlag, 1);
  }
  __syncthreads();
  const bool isf32 = (sFlag != 0);

  // ---- B-spline control pulses (512 threads: one pass) ----
  {
    float kn[20];
    kn[0] = 0.f; kn[1] = 0.f; kn[2] = 0.f;
    #pragma unroll
    for (int q = 0; q < 14; ++q) kn[3 + q] = (float)q / 13.0f;
    kn[17] = 1.f; kn[18] = 1.f; kn[19] = 1.f;
    const float t = (float)tid * DTF;
    float B[19];
    #pragma unroll
    for (int q = 0; q < 19; ++q) B[q] = (kn[q] <= t && t < kn[q+1]) ? 1.f : 0.f;
    #pragma unroll
    for (int d = 1; d <= 3; ++d) {
      #pragma unroll
      for (int q = 0; q + d < 19; ++q) {
        float ld = kn[q+d]   - kn[q];
        float rd = kn[q+d+1] - kn[q+1];
        float lv = (ld > 0.f) ? (t - kn[q])     / ld * B[q]   : 0.f;
        float rv = (rd > 0.f) ? (kn[q+d+1] - t) / rd * B[q+1] : 0.f;
        B[q] = lv + rv;
      }
    }
    #pragma unroll
    for (int c = 0; c < NC; ++c) {
      float s = 0.f;
      #pragma unroll
      for (int q = 0; q < NPAR; ++q) s += B[q] * ldval(g_params, q*NC + c, isf32);
      sU[tid][c] = s;
    }
  }

  // ---- constants staging (threads 0..255, elementwise (i,j)) ----
  if (tid < 256) {
    float* scr = sPops[0];   // planes: 0=G0r 1=G0i 2+2c=Gc_r 3+2c=Gc_i
    const int i = tid >> 4, j = tid & 15;
    const int ij = i*16 + j, ji = j*16 + i;
    float h0r = 0.5f * (ldval(g_H0re, ij, isf32) + ldval(g_H0re, ji, isf32));
    float h0i = 0.5f * (ldval(g_H0im, ij, isf32) - ldval(g_H0im, ji, isf32));
    float ldr = 0.f, ldi = 0.f;
    for (int k = 0; k < KL; ++k) {
      #pragma unroll
      for (int m = 0; m < DIM; ++m) {
        float ar = ldval(g_Lre, k*256 + m*16 + i, isf32), ai = ldval(g_Lim, k*256 + m*16 + i, isf32);
        float br = ldval(g_Lre, k*256 + m*16 + j, isf32), bi = ldval(g_Lim, k*256 + m*16 + j, isf32);
        ldr += ar*br + ai*bi;
        ldi += ar*bi - ai*br;
      }
    }
    scr[0*256 + ij] =  h0i - 0.5f*ldr;   // G0r
    scr[1*256 + ij] = -h0r - 0.5f*ldi;   // G0i
    #pragma unroll
    for (int c = 0; c < NC; ++c) {
      float hr = 0.5f * (ldval(g_Hcre, c*256 + ij, isf32) + ldval(g_Hcre, c*256 + ji, isf32));
      float hi = 0.5f * (ldval(g_Hcim, c*256 + ij, isf32) - ldval(g_Hcim, c*256 + ji, isf32));
      scr[(2 + 2*c)*256 + ij] =  hi;
      scr[(3 + 2*c)*256 + ij] = -hr;
    }
    // L': RNE hi/lo split
    #pragma unroll
    for (int k = 0; k < KL; ++k) {
      float lr = ldval(g_Lre, k*256 + ij, isf32);
      float li = ldval(g_Lim, k*256 + ij, isf32);
      unsigned short h;
      h = f2bf(lr); sLh[k][i*BST + j]      = h; sLl[k][i*BST + j]      = f2bf(lr - bf2f(h));
      h = f2bf(li); sLh[k][i*BST + 16 + j] = h; sLl[k][i*BST + 16 + j] = f2bf(li - bf2f(h));
    }
    // rho^T'(0), both chains
    #pragma unroll
    for (int c = 0; c < 2; ++c) {
      const int bb = b0 + c;
      float r0 = ldval(g_r0re, bb*256 + ij, isf32);
      float m0 = ldval(g_r0im, bb*256 + ij, isf32);
      unsigned short h, l;
      split2(r0, h, l); sPh[c][j*BST + i]      = h; sPl[c][j*BST + i]      = l;
      split2(m0, h, l); sPh[c][j*BST + 16 + i] = h; sPl[c][j*BST + 16 + i] = l;
    }
  }

  __syncthreads();   // scratch, sL, sP, sU visible

  // ---- per-wave preloads ----
  short8 Ah, Al;                    // wv0/1: G frag (rebuilt once per iteration)
  short8 TrBh, TrBl, TiBh, TiBl;    // wv2-5: T^T B-operands (L-derived constants)
  short8 JBh[KL], JBl[KL];          // wv6: straight Lf; wv7: swap+neg
  float  G0v[8], Gcv[NC][8];        // wv0/1
  float  rmA[4] = {0.f,0.f,0.f,0.f};// wv6: rho_re chain0; wv7: rho_im chain0 (C-layout)
  float  rmB[4] = {0.f,0.f,0.f,0.f};// same for chain1

  if (wv < 2) {
    const int comp = (fq < 2) ? 0 : 1;
    const int base = (fq & 1) * 8;
    const float* scr = sPops[0];
    {
      const float* s0 = &scr[comp*256 + fm*16 + base];
      f32x4 va = *(const f32x4*)s0, vb = *(const f32x4*)(s0 + 4);
      #pragma unroll
      for (int q = 0; q < 4; ++q) { G0v[q] = va[q]; G0v[4+q] = vb[q]; }
    }
    #pragma unroll
    for (int c = 0; c < NC; ++c) {
      const float* s0 = &scr[(2 + 2*c + comp)*256 + fm*16 + base];
      f32x4 va = *(const f32x4*)s0, vb = *(const f32x4*)(s0 + 4);
      #pragma unroll
      for (int q = 0; q < 4; ++q) { Gcv[c][q] = va[q]; Gcv[c][4+q] = vb[q]; }
    }
    f32x4 uv = *(const f32x4*)&sU[0][0];
    float gv[8];
    #pragma unroll
    for (int q = 0; q < 8; ++q)
      gv[q] = G0v[q] + uv[0]*Gcv[0][q] + uv[1]*Gcv[1][q] + uv[2]*Gcv[2][q] + uv[3]*Gcv[3][q];
    pack8(gv, Ah, Al);
  } else if (wv < 6) {
    const int k = wv - 2;
    TiBh = ldfrag(&sLh[k][fOff]);
    TiBl = ldfrag(&sLl[k][fOff]);
    TrBh = (fq >= 2) ? negbf8(TiBh) : TiBh;
    TrBl = (fq >= 2) ? negbf8(TiBl) : TiBl;
  } else if (wv == 6) {
    #pragma unroll
    for (int k = 0; k < KL; ++k) { JBh[k] = ldfrag(&sLh[k][fOff]); JBl[k] = ldfrag(&sLl[k][fOff]); }
    #pragma unroll
    for (int q = 0; q < 4; ++q) {
      rmA[q] = ldval(g_r0re, b0*256 + (row0+q)*16 + fm, isf32);
      rmB[q] = ldval(g_r0re, b1*256 + (row0+q)*16 + fm, isf32);
    }
  } else {
    #pragma unroll
    for (int k = 0; k < KL; ++k) {
      short8 h = ldfrag(&sLh[k][fOffS]);
      short8 l = ldfrag(&sLl[k][fOffS]);
      if (fq < 2) { h = negbf8(h); l = negbf8(l); }
      JBh[k] = h; JBl[k] = l;
    }
    #pragma unroll
    for (int q = 0; q < 4; ++q) {
      rmA[q] = ldval(g_r0im, b0*256 + (row0+q)*16 + fm, isf32);
      rmB[q] = ldval(g_r0im, b1*256 + (row0+q)*16 + fm, isf32);
    }
  }

// ---- phase-1 work for chain c (M on wv0/1, T on wv2-5) — verbatim 8-wave code ----
#define P1WORK(c) do { \
    if (wv < 2) { \
      short8 Bh, Bl; \
      if (wv == 0) { \
        Bh = ldfrag(&sPh[c][fOff]);  Bl = ldfrag(&sPl[c][fOff]); \
        if (fq >= 2) { Bh = negbf8(Bh); Bl = negbf8(Bl); } \
      } else { \
        Bh = ldfrag(&sPh[c][fOffS]); Bl = ldfrag(&sPl[c][fOffS]); \
      } \
      f32x4 a = {0.f,0.f,0.f,0.f}; \
      a = mm3(Ah, Al, Bh, Bl, a); \
      float* Mn = (wv == 0) ? sMr[c]  : sMi[c]; \
      float* Mt = (wv == 0) ? sMrT[c] : sMiT[c]; \
      _Pragma("unroll") \
      for (int r = 0; r < 4; ++r) Mn[(row0 + r)*FST + fm] = a[r]; \
      *(f32x4*)&Mt[fm*FST + row0] = a; \
    } else if (wv < 6) { \
      const int k = wv - 2; \
      short8 Arh = ldfrag(&sPh[c][fOff]),  Arl = ldfrag(&sPl[c][fOff]); \
      short8 Aih = ldfrag(&sPh[c][fOffS]), Ail = ldfrag(&sPl[c][fOffS]); \
      f32x4 tr = {0.f,0.f,0.f,0.f}, ti = {0.f,0.f,0.f,0.f}; \
      tr = mm3(Arh, Arl, TrBh, TrBl, tr); \
      ti = mm3(Aih, Ail, TiBh, TiBl, ti); \
      short4v HR, LR, HI2, LI2; \
      pack4(tr, HR, LR); \
      pack4(ti, HI2, LI2); \
      *(short4v*)&sTh[c][k][fm*BST + row0]      = HR; \
      *(short4v*)&sTl[c][k][fm*BST + row0]      = LR; \
      *(short4v*)&sTh[c][k][fm*BST + 16 + row0] = HI2; \
      *(short4v*)&sTl[c][k][fm*BST + 16 + row0] = LI2; \
    } \
  } while (0)

// ---- phase-2 work for chain c at step tt (J + rho update on wv6/7) — verbatim 8-wave code ----
#define P2WORK(c, tt) do { \
    if (wv >= 6) { \
      short8 T0h = ldfrag(&sTh[c][0][fOff]), T0l = ldfrag(&sTl[c][0][fOff]); \
      short8 T1h = ldfrag(&sTh[c][1][fOff]), T1l = ldfrag(&sTl[c][1][fOff]); \
      short8 T2h = ldfrag(&sTh[c][2][fOff]), T2l = ldfrag(&sTl[c][2][fOff]); \
      short8 T3h = ldfrag(&sTh[c][3][fOff]), T3l = ldfrag(&sTl[c][3][fOff]); \
      f32x4 a0 = {0.f,0.f,0.f,0.f}, a1 = {0.f,0.f,0.f,0.f}, \
            a2 = {0.f,0.f,0.f,0.f}, a3 = {0.f,0.f,0.f,0.f}; \
      a0 = mm3(JBh[0], JBl[0], T0h, T0l, a0); \
      a1 = mm3(JBh[1], JBl[1], T1h, T1l, a1); \
      a2 = mm3(JBh[2], JBl[2], T2h, T2l, a2); \
      a3 = mm3(JBh[3], JBl[3], T3h, T3l, a3); \
      const float* Mt_ = (wv == 6) ? sMrT[c] : sMiT[c]; \
      const float* Mn_ = (wv == 6) ? sMr[c]  : sMi[c]; \
      f32x4 d1 = *(const f32x4*)&Mt_[fm*FST + row0]; \
      f32x4 d2 = *(const f32x4*)&Mn_[fm*FST + row0]; \
      float* rmp = (c) ? rmB : rmA; \
      f32x4 rv; short4v HH, LL; \
      if (wv == 6) { \
        _Pragma("unroll") \
        for (int q = 0; q < 4; ++q) { \
          rmp[q] += DTF * (d1[q] + d2[q] + ((a0[q] + a1[q]) + (a2[q] + a3[q]))); \
          rv[q] = rmp[q]; \
        } \
        pack4(rv, HH, LL); \
        *(short4v*)&sPh[c][fm*BST + row0] = HH; \
        *(short4v*)&sPl[c][fm*BST + row0] = LL; \
        if ((unsigned)(fm - row0) < 4u) sPops[c][(tt)*DIM + fm] = rmp[fm - row0]; \
      } else { \
        _Pragma("unroll") \
        for (int q = 0; q < 4; ++q) { \
          rmp[q] += DTF * (d1[q] - d2[q] - ((a0[q] + a1[q]) + (a2[q] + a3[q]))); \
          rv[q] = rmp[q]; \
        } \
        pack4(rv, HH, LL); \
        *(short4v*)&sPh[c][fm*BST + 16 + row0] = HH; \
        *(short4v*)&sPl[c][fm*BST + 16 + row0] = LL; \
      } \
    } \
  } while (0)

  // ---- main loop: per iteration i, first phase = P1(A,i) ∥ P2(B,i-1),
  //      second phase = P2(A,i) ∥ P1(B,i). 2 barriers/iter; tail drains chain B. ----
  #pragma unroll 1
  for (int i = 0; i <= NTS; ++i) {
    __syncthreads();                 // B1: sP(A,i) + sT/sM(B,i-1) visible
    if (i < NTS) P1WORK(0);
    if (i > 0)   P2WORK(1, i-1);
    if (i == NTS) break;
    __syncthreads();                 // B2: sT/sM(A,i) + sP(B,i) visible
    P2WORK(0, i);
    P1WORK(1);
    if (wv < 2) {
      // G-rebuild for step i+1 (serves BOTH chains next iteration; registers only)
      const int tn = (i + 1 < NTS) ? (i + 1) : (NTS - 1);
      f32x4 uv = *(const f32x4*)&sU[tn][0];
      float gv[8];
      #pragma unroll
      for (int q = 0; q < 8; ++q)
        gv[q] = G0v[q] + uv[0]*Gcv[0][q] + uv[1]*Gcv[1][q] + uv[2]*Gcv[2][q] + uv[3]*Gcv[3][q];
      pack8(gv, Ah, Al);
    }
  }

  // ---- final coalesced pops flush (float4), both chains ----
  __syncthreads();
  #pragma unroll
  for (int c = 0; c < 2; ++c) {
    const int bb = b0 + c;
    #pragma unroll
    for (int s = 0; s < NTS*DIM/(512*4); ++s) {
      int idx = (s*512 + tid) * 4;               // idx = t*16 + d, d 4-aligned
      int tt = idx >> 4, dd = idx & 15;
      *(float4*)&g_out[tt*(BATCH*DIM) + bb*DIM + dd] = *(const float4*)&sPops[c][idx];
    }
  }
}

extern "C" void kernel_launch(void* const* d_in, const int* in_sizes, int n_in,
                              void* d_out, int out_size, void* d_ws, size_t ws_size,
                              hipStream_t stream) {
  (void)out_size; (void)d_ws; (void)ws_size;
  const void *P, *H0r, *H0i, *Hcr, *Hci, *Lr, *Li, *R0r, *R0i;
  int idx64 = -1;
  for (int q = 0; q < n_in; ++q) if (in_sizes[q] == 64) idx64 = q;
  if (idx64 == 6) {   // alphabetical fallback
    H0i = d_in[0]; H0r = d_in[1];
    Hci = d_in[2]; Hcr = d_in[3];
    Li  = d_in[4]; Lr  = d_in[5];
    P   = d_in[6];
    R0i = d_in[7]; R0r = d_in[8];
  } else {            // documented setup_inputs() dict order (R4-verified)
    P   = d_in[0];
    H0r = d_in[1]; H0i = d_in[2];
    Hcr = d_in[3]; Hci = d_in[4];
    Lr  = d_in[5]; Li  = d_in[6];
    R0r = d_in[7]; R0i = d_in[8];
  }
  lindblad_evolve<<<dim3(BATCH/2), dim3(512), 0, stream>>>(
      P, H0r, H0i, Hcr, Hci, Lr, Li, R0r, R0i, (float*)d_out);
}